// Round 14
// baseline (1006.570 us; speedup 1.0000x reference)
//
#include <hip/hip_runtime.h>

typedef float  f32x4  __attribute__((ext_vector_type(4)));
typedef float  f32x16 __attribute__((ext_vector_type(16)));
typedef int    i32x4  __attribute__((ext_vector_type(4)));
typedef int    i32x8  __attribute__((ext_vector_type(8)));

#define AS1 __attribute__((address_space(1)))
#define AS3 __attribute__((address_space(3)))

// ---- software float -> OCP e4m3fn (RNE), valid for |x| <= 448 ----
__device__ __forceinline__ unsigned int f2e4m3(float x){
    union{float f; unsigned u;} v; v.f = x;
    unsigned s = (v.u >> 24) & 0x80u;
    float ax = fabsf(x);
    if (ax > 448.0f) ax = 448.0f;
    if (ax < 0.015625f){
        int d = (int)__builtin_rintf(ax * 512.0f);
        return s | (unsigned)d;
    }
    v.f = ax;
    unsigned u = v.u + 0x7ffffu + ((v.u >> 20) & 1u);
    unsigned E = (u >> 23) - 120u;
    unsigned M = (u >> 20) & 7u;
    return s | (E << 3) | M;
}

// ---- 4 floats -> packed 4x e4m3 (HW cvt if available) ----
__device__ __forceinline__ unsigned int pk4(float x0, float x1, float x2, float x3){
#if __has_builtin(__builtin_amdgcn_cvt_pk_fp8_f32)
    int u = __builtin_amdgcn_cvt_pk_fp8_f32(x0, x1, 0, false);
    u     = __builtin_amdgcn_cvt_pk_fp8_f32(x2, x3, u, true);
    return (unsigned)u;
#else
    return f2e4m3(x0) | (f2e4m3(x1) << 8) | (f2e4m3(x2) << 16) | (f2e4m3(x3) << 24);
#endif
}

__device__ __forceinline__ void gload16(const unsigned char* g, const char* l){
    __builtin_amdgcn_global_load_lds((const AS1 void*)g, (AS3 void*)l, 16, 0, 0);
}

__device__ __forceinline__ i32x8 ld_frag(const char* p0, const char* p1){
    i32x4 lo = *(const i32x4*)p0;
    i32x4 hi = *(const i32x4*)p1;
    return __builtin_shufflevector(lo, hi, 0,1,2,3,4,5,6,7);
}

#define GBAR() do{ asm volatile("" ::: "memory"); __builtin_amdgcn_s_barrier(); \
                   asm volatile("" ::: "memory"); }while(0)
#define VMW(N)  asm volatile("s_waitcnt vmcnt(" #N ")" ::: "memory")

// ---------------------------------------------------------------------------
// Row l2-normalize [rows][1024] f32 -> fp8 e4m3 *16 (2^-4), ROW-MAJOR.
// ---------------------------------------------------------------------------
__global__ __launch_bounds__(256) void norm_rows_fp8_rm(const float* __restrict__ in,
                                                        unsigned int* __restrict__ out){
    const int row = blockIdx.x;
    const int t   = threadIdx.x;
    f32x4 x = ((const f32x4*)(in + (size_t)row * 1024))[t];
    float ss = x[0]*x[0] + x[1]*x[1] + x[2]*x[2] + x[3]*x[3];
    #pragma unroll
    for (int o = 32; o > 0; o >>= 1) ss += __shfl_xor(ss, o);
    __shared__ float red[4];
    if ((t & 63) == 0) red[t >> 6] = ss;
    __syncthreads();
    float tot = red[0] + red[1] + red[2] + red[3];
    float inv = 16.0f / fmaxf(sqrtf(tot), 1e-12f);
    out[(size_t)row * 256 + t] = pk4(x[0]*inv, x[1]*inv, x[2]*inv, x[3]*inv);
}

// ---------------------------------------------------------------------------
// Row l2-normalize [rows][1024] f32 -> fp8 e4m3 *16 (2^-4), FRAGMENT-LINEAR
// NT=16. chunk(f,t)=2048B at ((row>>5)*16+t)*2048; lane l: row l&31, k-half l>>5.
// ---------------------------------------------------------------------------
__global__ __launch_bounds__(256) void norm_rows_fp8_fl(const float* __restrict__ in,
                                                        unsigned char* __restrict__ out){
    const int row = blockIdx.x;
    const int t   = threadIdx.x;
    f32x4 x = ((const f32x4*)(in + (size_t)row * 1024))[t];
    float ss = x[0]*x[0] + x[1]*x[1] + x[2]*x[2] + x[3]*x[3];
    #pragma unroll
    for (int o = 32; o > 0; o >>= 1) ss += __shfl_xor(ss, o);
    __shared__ float red[4];
    if ((t & 63) == 0) red[t >> 6] = ss;
    __syncthreads();
    float tot = red[0] + red[1] + red[2] + red[3];
    float inv = 16.0f / fmaxf(sqrtf(tot), 1e-12f);
    unsigned u = pk4(x[0]*inv, x[1]*inv, x[2]*inv, x[3]*inv);
    size_t addr = ((size_t)(row >> 5) * 16 + (t >> 4)) * 2048
                + (size_t)((t >> 3) & 1) * 1024
                + (size_t)(row & 31) * 32 + ((4 * t) & 31);
    *(unsigned int*)(out + addr) = u;
}

// ---------------------------------------------------------------------------
// offset [C=2048][D=1024] f32 -> offt FRAGMENT-LINEAR fp8 *64 (2^-6):
// rows = d (1024), K = c (2048), NT=32. Fused sum(offset^2) atomic. (r11-validated)
// ---------------------------------------------------------------------------
__global__ __launch_bounds__(256) void transpose_off(const float* __restrict__ off,
                                                     unsigned char* __restrict__ offt,
                                                     float* __restrict__ reg_out){
    __shared__ unsigned char t_lds[64][68];
    const int t  = threadIdx.x;
    const int c0 = blockIdx.x * 64;
    const int d0 = blockIdx.y * 64;
    float ss = 0.f;
    #pragma unroll
    for (int p = 0; p < 4; ++p){
        int c  = p * 16 + (t >> 4);
        int dq = t & 15;
        f32x4 v = *(const f32x4*)(off + (size_t)(c0 + c) * 1024 + d0 + dq * 4);
        ss += v[0]*v[0] + v[1]*v[1] + v[2]*v[2] + v[3]*v[3];
        unsigned u = pk4(v[0]*64.0f, v[1]*64.0f, v[2]*64.0f, v[3]*64.0f);
        #pragma unroll
        for (int j = 0; j < 4; ++j) t_lds[dq * 4 + j][c] = (unsigned char)(u >> (8*j));
    }
    __syncthreads();
    #pragma unroll
    for (int i = 0; i < 4; ++i){
        int byte_o = (t + 256 * i) * 4;
        int fs  = byte_o >> 11;
        int rem = byte_o & 2047;
        int dl  = fs * 32 + ((rem >> 5) & 31);
        int cl  = ((rem >> 10) & 1) * 32 + (rem & 31);
        unsigned int v = *(const unsigned int*)&t_lds[dl][cl];
        size_t f = (size_t)((d0 >> 5) + fs);
        *(unsigned int*)(offt + (f * 32 + (c0 >> 6)) * 2048 + rem) = v;
    }
    #pragma unroll
    for (int o = 32; o > 0; o >>= 1) ss += __shfl_xor(ss, o);
    __shared__ float red[4];
    if ((t & 63) == 0) red[t >> 6] = ss;
    __syncthreads();
    if (t == 0) atomicAdd(reg_out, red[0] + red[1] + red[2] + red[3]);
}

// ---------------------------------------------------------------------------
// GEMM1 (r13-validated hybrid): A row-major via LDS, B frag-linear global.
// 256x256 tile, 512 thr (8 waves 2Mx4N, wave 128x64). A tri-buffer 48KB.
// EPI==1: Wout = e4m3(exp(10*acc-10)*1024) row-major (ldw bytes)
// ---------------------------------------------------------------------------
template<int EPI, int SA, int SB>
__global__ __launch_bounds__(512, 2)
void gemm_hyb(const unsigned char* __restrict__ A, int lda,
              const unsigned char* __restrict__ B,
              int K,
              unsigned char* __restrict__ Wout, int ldw,
              const float* __restrict__ Cadd, float* __restrict__ Fout, int ldo)
{
    extern __shared__ char smem[];
    const int tid = threadIdx.x;
    int bx = blockIdx.x, by = blockIdx.y;
    {
        const int gx = gridDim.x, gy = gridDim.y;
        const int nwg = gx * gy;
        if ((nwg & 7) == 0){
            const int lid = bx + gx * by;
            const int q   = nwg >> 3;
            const int n   = (lid & 7) * q + (lid >> 3);
            const int sh  = 31 - __clz(gy);
            bx = n >> sh;
            by = n & (gy - 1);
        }
    }
    const int m0  = bx * 256;
    const int n0  = by * 256;
    const int wid = tid >> 6, lane = tid & 63;
    const int wr  = wid >> 2, wc = wid & 3;
    const int l31 = lane & 31, hg = lane >> 5;
    const int NT  = K >> 6;

    const int srow = tid >> 2;
    const int sg   = (tid & 3) ^ ((tid >> 3) & 3);
    const unsigned char* sA = A + (size_t)(m0 + srow) * lda + sg * 16;
    const int lp = tid * 16;
    auto stgA = [&](int buf, int ke){
        char* wb = smem + buf * 16384;
        gload16(sA + ke, wb + lp);
        gload16(sA + (size_t)128 * lda + ke, wb + 8192 + lp);
    };

    int aoff[4][2];
    #pragma unroll
    for (int m = 0; m < 4; ++m){
        int row = wr * 128 + m * 32 + l31;
        int sw  = (row >> 1) & 3;
        aoff[m][0] = row * 64 + (((hg << 1) | 0) ^ sw) * 16;
        aoff[m][1] = row * 64 + (((hg << 1) | 1) ^ sw) * 16;
    }
    const char* pB[2];
    #pragma unroll
    for (int n = 0; n < 2; ++n)
        pB[n] = (const char*)B
              + (size_t)(((n0 + wc * 64 + n * 32) >> 5) * NT) * 2048 + lane * 32;

    f32x16 acc[4][2] = {};
    i32x8 fa[4], bcur[2], bnxt[2];

#define MFMA8(bv) { __builtin_amdgcn_s_setprio(1); \
    _Pragma("unroll") for (int mi = 0; mi < 4; ++mi) \
    _Pragma("unroll") for (int ni = 0; ni < 2; ++ni) \
        acc[mi][ni] = __builtin_amdgcn_mfma_scale_f32_32x32x64_f8f6f4( \
            fa[mi], bv[ni], acc[mi][ni], 0, 0, 0, SA, 0, SB); \
    __builtin_amdgcn_s_setprio(0); }

    stgA(0, 0);
    stgA(1, 64);
    #pragma unroll
    for (int n = 0; n < 2; ++n) bcur[n] = ld_frag(pB[n], pB[n] + 16);
    VMW(6);
    GBAR();

    int bufc = 0;
    #pragma unroll 1
    for (int t = 0; t < NT - 1; ++t){
        const char* rb = smem + bufc * 16384;
        #pragma unroll
        for (int m = 0; m < 4; ++m)
            fa[m] = ld_frag(rb + aoff[m][0], rb + aoff[m][1]);
        {
            const size_t o = (size_t)(t + 1) * 2048;
            #pragma unroll
            for (int n = 0; n < 2; ++n) bnxt[n] = ld_frag(pB[n] + o, pB[n] + o + 16);
        }
        MFMA8(bcur);
        VMW(4);
        GBAR();
        if (t + 2 < NT){
            int bs = bufc + 2; if (bs >= 3) bs -= 3;
            stgA(bs, (t + 2) * 64);
        }
        bcur[0] = bnxt[0]; bcur[1] = bnxt[1];
        ++bufc; if (bufc == 3) bufc = 0;
    }
    {
        const char* rb = smem + bufc * 16384;
        #pragma unroll
        for (int m = 0; m < 4; ++m)
            fa[m] = ld_frag(rb + aoff[m][0], rb + aoff[m][1]);
        MFMA8(bcur);
    }
#undef MFMA8

    asm volatile("s_nop 7\n\ts_nop 7");

    #pragma unroll
    for (int m = 0; m < 4; ++m){
        #pragma unroll
        for (int n = 0; n < 2; ++n){
            const int grb = m0 + wr * 128 + m * 32;
            const int gc  = n0 + wc * 64  + n * 32 + l31;
            if (EPI == 1){
                #pragma unroll
                for (int q = 0; q < 4; ++q){
                    const int row0 = grb + 8 * q + 4 * hg;
                    float w0 = exp2f(fmaf(14.4269504f, acc[m][n][4*q+0], -4.4269504f));
                    float w1 = exp2f(fmaf(14.4269504f, acc[m][n][4*q+1], -4.4269504f));
                    float w2 = exp2f(fmaf(14.4269504f, acc[m][n][4*q+2], -4.4269504f));
                    float w3 = exp2f(fmaf(14.4269504f, acc[m][n][4*q+3], -4.4269504f));
                    unsigned u = pk4(w0, w1, w2, w3);
                    unsigned char* p = Wout + (size_t)row0 * ldw + gc;
                    p[0]                = (unsigned char)u;
                    p[(size_t)ldw]      = (unsigned char)(u >> 8);
                    p[(size_t)ldw * 2]  = (unsigned char)(u >> 16);
                    p[(size_t)ldw * 3]  = (unsigned char)(u >> 24);
                }
            } else {
                #pragma unroll
                for (int r = 0; r < 16; ++r){
                    const int row = (r & 3) + 8 * (r >> 2) + 4 * hg;
                    Fout[(size_t)(grb + row) * ldo + gc] =
                        Cadd[(size_t)(grb + row) * ldo + gc] + acc[m][n][r];
                }
            }
        }
    }
}

// ---------------------------------------------------------------------------
// GEMM2 + FUSED ROW-NORM: out[64 rows][1024] = l2norm(inp + W.offt^T) per row.
// Block tile 64x1024, K = C = 2048 bytes. 512 thr = 8 waves (2M x 4N):
// wave tile 32 rows x 256 cols -> acc[8] x f32x16 = 128 VGPR.
// A = W row-major fp8, LDS tri-buffer units of 64 rows x 256B (4 k-tiles),
//   granule-16 swizzle p ^= row&15 via pre-swizzled source; barrier only at
//   unit boundaries (every 4 k-tiles) -> compiler pipelines the unit body.
// B = offt frag-linear (NT=32), direct global, 2x4-frag ping-pong.
// Epilogue: v = inp + acc (scales applied by mfma_scale); row-ss via 5-step
// shfl_xor butterfly (rows live in one 32-lane half) + LDS cross-wc reduce;
// write normalized out directly. Eliminates the separate norm pass.
// ---------------------------------------------------------------------------
template<int SA, int SB>
__global__ __launch_bounds__(512, 2)
void gemm_norm(const unsigned char* __restrict__ W,      // [rows][2048] fp8
               const unsigned char* __restrict__ Boff,   // frag-linear NT=32
               const float* __restrict__ inp,
               float* __restrict__ out)
{
    extern __shared__ char smem[];             // 3 x 16 KiB A units
    const int tid = threadIdx.x;
    int b = blockIdx.x;
    {   // 1D bijective XCD swizzle (grid % 8 == 0)
        const int nwg = gridDim.x;
        if ((nwg & 7) == 0){ const int q = nwg >> 3; b = (b & 7) * q + (b >> 3); }
    }
    const int r0  = b * 64;
    const int wid = tid >> 6, lane = tid & 63;
    const int wr  = wid >> 2, wc = wid & 3;    // 2M x 4N; wave 32 x 256
    const int l31 = lane & 31, hg = lane >> 5;
    const int NT  = 32;                        // k-tiles (2048 / 64)
    const int NU  = 8;                         // units of 4 k-tiles

    // ---- A staging: unit = 64 rows x 16 granules(16B); thread covers
    // granules tid (rows 0-31) and tid+512 (rows 32-63); phys slot p of a row
    // holds logical p ^ (row & 15) -> pre-swizzled source column.
    const int s_row = tid >> 4;                // 0..31
    const int s_col = ((tid & 15) ^ (s_row & 15)) * 16;
    auto stgA = [&](int buf, int u){
        char* wb = smem + buf * 16384;
        const unsigned char* base = W + (size_t)u * 256 + s_col;
        gload16(base + (size_t)(r0 + s_row)      * 2048, wb + tid * 16);
        gload16(base + (size_t)(r0 + 32 + s_row) * 2048, wb + 8192 + tid * 16);
    };

    // ---- A frag ds offsets per kk (unit-relative, swizzled) ----
    int aoff[4][2];
    {
        const int row = wr * 32 + l31;
        const int sw  = row & 15;
        #pragma unroll
        for (int kk = 0; kk < 4; ++kk){
            aoff[kk][0] = row * 256 + ((kk * 4 + hg * 2 + 0) ^ sw) * 16;
            aoff[kk][1] = row * 256 + ((kk * 4 + hg * 2 + 1) ^ sw) * 16;
        }
    }

    // ---- B frag-linear pointers: col-block n -> frag (wc*8 + n) ----
    const char* pB[8];
    #pragma unroll
    for (int n = 0; n < 8; ++n)
        pB[n] = (const char*)Boff + (size_t)(wc * 8 + n) * NT * 2048 + lane * 32;

    f32x16 acc[8] = {};
    i32x8 fa, b0[4], b1[4];

    // ---- prologue: stage units 0,1; load B(0) both halves ----
    stgA(0, 0);
    stgA(1, 1);
    VMW(2);                                    // unit 0 landed (unit 1 in flight)
    #pragma unroll
    for (int n = 0; n < 4; ++n) b0[n] = ld_frag(pB[n],     pB[n] + 16);
    #pragma unroll
    for (int n = 0; n < 4; ++n) b1[n] = ld_frag(pB[n + 4], pB[n + 4] + 16);
    GBAR();

    #pragma unroll 1
    for (int u = 0; u < NU; ++u){
        const char* rb = smem + (u % 3) * 16384;
        #pragma unroll
        for (int kk = 0; kk < 4; ++kk){
            const int t = u * 4 + kk;
            fa = ld_frag(rb + aoff[kk][0], rb + aoff[kk][1]);
            const size_t on = (size_t)(t + 1 < NT ? t + 1 : NT - 1) * 2048;
            __builtin_amdgcn_s_setprio(1);
            #pragma unroll
            for (int n = 0; n < 4; ++n)
                acc[n] = __builtin_amdgcn_mfma_scale_f32_32x32x64_f8f6f4(
                    fa, b0[n], acc[n], 0, 0, 0, SA, 0, SB);
            __builtin_amdgcn_s_setprio(0);
            #pragma unroll
            for (int n = 0; n < 4; ++n) b0[n] = ld_frag(pB[n] + on, pB[n] + on + 16);
            __builtin_amdgcn_s_setprio(1);
            #pragma unroll
            for (int n = 0; n < 4; ++n)
                acc[n + 4] = __builtin_amdgcn_mfma_scale_f32_32x32x64_f8f6f4(
                    fa, b1[n], acc[n + 4], 0, 0, 0, SA, 0, SB);
            __builtin_amdgcn_s_setprio(0);
            #pragma unroll
            for (int n = 0; n < 4; ++n) b1[n] = ld_frag(pB[n+4] + on, pB[n+4] + on + 16);
        }
        if (u + 1 < NU) VMW(16);               // A(u+1) DMAs (oldest) retired
        GBAR();
        if (u + 2 < NU) stgA((u + 2) % 3, u + 2);
    }

    asm volatile("s_nop 7\n\ts_nop 7");

    // ---- fused epilogue: v = inp + acc; row l2-norm; write out ----
    // C/D: col = l31 (+n*32 +wc*256), row = (r&3) + 8*(r>>2) + 4*hg  (in [0,32))
    float ss[16];
    #pragma unroll
    for (int r = 0; r < 16; ++r) ss[r] = 0.f;
    const int grow0 = r0 + wr * 32;
    #pragma unroll
    for (int n = 0; n < 8; ++n){
        const int col = wc * 256 + n * 32 + l31;
        #pragma unroll
        for (int r = 0; r < 16; ++r){
            const int row = (r & 3) + 8 * (r >> 2) + 4 * hg;
            float vv = inp[(size_t)(grow0 + row) * 1024 + col] + acc[n][r];
            acc[n][r] = vv;
            ss[r] += vv * vv;
        }
    }
    #pragma unroll
    for (int m = 1; m <= 16; m <<= 1)
        #pragma unroll
        for (int r = 0; r < 16; ++r) ss[r] += __shfl_xor(ss[r], m);

    float* ssb = (float*)smem;                 // [64 rows][4 wc] = 1 KiB
    GBAR();                                    // k-loop LDS reads all retired
    if (l31 == 0){
        #pragma unroll
        for (int r = 0; r < 16; ++r){
            const int row = (r & 3) + 8 * (r >> 2) + 4 * hg;
            ssb[(wr * 32 + row) * 4 + wc] = ss[r];
        }
    }
    GBAR();
    #pragma unroll
    for (int r = 0; r < 16; ++r){
        const int row = (r & 3) + 8 * (r >> 2) + 4 * hg;
        const float* q = &ssb[(wr * 32 + row) * 4];
        float tot = q[0] + q[1] + q[2] + q[3];
        float inv = 1.0f / fmaxf(sqrtf(tot), 1e-12f);
        const size_t rbase = (size_t)(grow0 + row) * 1024;
        #pragma unroll
        for (int n = 0; n < 8; ++n){
            const int col = wc * 256 + n * 32 + l31;
            out[rbase + col] = acc[n][r] * inv;
        }
    }
}

// ---------------------------------------------------------------------------
extern "C" void kernel_launch(void* const* d_in, const int* in_sizes, int n_in,
                              void* d_out, int out_size, void* d_ws, size_t ws_size,
                              hipStream_t stream)
{
    (void)n_in; (void)out_size;
    const float* inp = (const float*)d_in[0];
    const float* pos = (const float*)d_in[1];
    const float* off = (const float*)d_in[2];
    float* out = (float*)d_out;

    const int D = 1024, C = 2048;
    const int N = in_sizes[0] / D;            // 32768

    // workspace (bytes): b_fp8(frag-lin)[C*D] | offt(frag-lin)[D*C]
    //                  | a_fp8(row-major)[Mc*D] | w_buf(row-major)[Mc*C]
    unsigned char* b_fp8 = (unsigned char*)d_ws;
    unsigned char* offt  = b_fp8 + (size_t)C * D;
    unsigned char* a_fp8 = offt + (size_t)D * C;
    size_t fixed = (size_t)C * D * 2;
    size_t avail = ws_size > fixed ? ws_size - fixed : 0;
    int Mc = 256;
    for (int cand = N; cand >= 256; cand >>= 1){
        if ((size_t)cand * (size_t)(D + C) <= avail){ Mc = cand; break; }
    }
    if (Mc > N) Mc = N;
    unsigned char* w_buf = a_fp8 + (size_t)Mc * D;

    hipFuncSetAttribute(reinterpret_cast<const void*>(&gemm_hyb<1,123,123>),
                        hipFuncAttributeMaxDynamicSharedMemorySize, 49152);
    hipFuncSetAttribute(reinterpret_cast<const void*>(&gemm_norm<117,121>),
                        hipFuncAttributeMaxDynamicSharedMemorySize, 49152);

    float* reg_out = out + (size_t)N * D;
    hipMemsetAsync(reg_out, 0, sizeof(float), stream);

    transpose_off<<<dim3(C / 64, D / 64), 256, 0, stream>>>(off, offt, reg_out);
    norm_rows_fp8_fl<<<C, 256, 0, stream>>>(pos, b_fp8);

    // scales (e8m0, 2^(b-127)): GEMM1 a,pos *16 -> 123,123;
    // GEMM2 W *1024 -> 117, offt *64 -> 121.
    for (int r0 = 0; r0 < N; r0 += Mc){
        norm_rows_fp8_rm<<<Mc, 256, 0, stream>>>(inp + (size_t)r0 * D, (unsigned int*)a_fp8);
        // GEMM1: W[Mc][C] = e4m3(1024 * exp(10*(a.b^T) - 10)), row-major
        gemm_hyb<1,123,123><<<dim3(Mc / 256, C / 256), 512, 49152, stream>>>(
            a_fp8, D, b_fp8, D, w_buf, C, nullptr, nullptr, 0);
        // GEMM2 + fused row-norm: out[Mc][D] = l2norm(inp + W.offt^T)
        gemm_norm<117,121><<<Mc / 64, 512, 49152, stream>>>(
            w_buf, offt, inp + (size_t)r0 * D, out + (size_t)r0 * D);
    }
}

// Round 15
// 628.884 us; speedup vs baseline: 1.6006x; 1.6006x over previous
//
#include <hip/hip_runtime.h>

typedef float  f32x4  __attribute__((ext_vector_type(4)));
typedef float  f32x16 __attribute__((ext_vector_type(16)));
typedef int    i32x4  __attribute__((ext_vector_type(4)));
typedef int    i32x8  __attribute__((ext_vector_type(8)));

#define AS1 __attribute__((address_space(1)))
#define AS3 __attribute__((address_space(3)))

// ---- software float -> OCP e4m3fn (RNE), valid for |x| <= 448 ----
__device__ __forceinline__ unsigned int f2e4m3(float x){
    union{float f; unsigned u;} v; v.f = x;
    unsigned s = (v.u >> 24) & 0x80u;
    float ax = fabsf(x);
    if (ax > 448.0f) ax = 448.0f;
    if (ax < 0.015625f){
        int d = (int)__builtin_rintf(ax * 512.0f);
        return s | (unsigned)d;
    }
    v.f = ax;
    unsigned u = v.u + 0x7ffffu + ((v.u >> 20) & 1u);
    unsigned E = (u >> 23) - 120u;
    unsigned M = (u >> 20) & 7u;
    return s | (E << 3) | M;
}

// ---- 4 floats -> packed 4x e4m3 (HW cvt if available) ----
__device__ __forceinline__ unsigned int pk4(float x0, float x1, float x2, float x3){
#if __has_builtin(__builtin_amdgcn_cvt_pk_fp8_f32)
    int u = __builtin_amdgcn_cvt_pk_fp8_f32(x0, x1, 0, false);
    u     = __builtin_amdgcn_cvt_pk_fp8_f32(x2, x3, u, true);
    return (unsigned)u;
#else
    return f2e4m3(x0) | (f2e4m3(x1) << 8) | (f2e4m3(x2) << 16) | (f2e4m3(x3) << 24);
#endif
}

__device__ __forceinline__ void gload16(const unsigned char* g, const char* l){
    __builtin_amdgcn_global_load_lds((const AS1 void*)g, (AS3 void*)l, 16, 0, 0);
}

__device__ __forceinline__ i32x8 ld_frag(const char* p0, const char* p1){
    i32x4 lo = *(const i32x4*)p0;
    i32x4 hi = *(const i32x4*)p1;
    return __builtin_shufflevector(lo, hi, 0,1,2,3,4,5,6,7);
}

#define GBAR() do{ asm volatile("" ::: "memory"); __builtin_amdgcn_s_barrier(); \
                   asm volatile("" ::: "memory"); }while(0)
#define VMW(N)  asm volatile("s_waitcnt vmcnt(" #N ")" ::: "memory")

// ---------------------------------------------------------------------------
// Row l2-normalize [rows][1024] f32 -> fp8 e4m3 *16 (2^-4), ROW-MAJOR.
// ---------------------------------------------------------------------------
__global__ __launch_bounds__(256) void norm_rows_fp8_rm(const float* __restrict__ in,
                                                        unsigned int* __restrict__ out){
    const int row = blockIdx.x;
    const int t   = threadIdx.x;
    f32x4 x = ((const f32x4*)(in + (size_t)row * 1024))[t];
    float ss = x[0]*x[0] + x[1]*x[1] + x[2]*x[2] + x[3]*x[3];
    #pragma unroll
    for (int o = 32; o > 0; o >>= 1) ss += __shfl_xor(ss, o);
    __shared__ float red[4];
    if ((t & 63) == 0) red[t >> 6] = ss;
    __syncthreads();
    float tot = red[0] + red[1] + red[2] + red[3];
    float inv = 16.0f / fmaxf(sqrtf(tot), 1e-12f);
    out[(size_t)row * 256 + t] = pk4(x[0]*inv, x[1]*inv, x[2]*inv, x[3]*inv);
}

// ---------------------------------------------------------------------------
// Row l2-normalize [rows][1024] f32 -> fp8 e4m3 *16 (2^-4), FRAGMENT-LINEAR
// NT=16. chunk(f,t)=2048B at ((row>>5)*16+t)*2048; lane l: row l&31, k-half l>>5.
// ---------------------------------------------------------------------------
__global__ __launch_bounds__(256) void norm_rows_fp8_fl(const float* __restrict__ in,
                                                        unsigned char* __restrict__ out){
    const int row = blockIdx.x;
    const int t   = threadIdx.x;
    f32x4 x = ((const f32x4*)(in + (size_t)row * 1024))[t];
    float ss = x[0]*x[0] + x[1]*x[1] + x[2]*x[2] + x[3]*x[3];
    #pragma unroll
    for (int o = 32; o > 0; o >>= 1) ss += __shfl_xor(ss, o);
    __shared__ float red[4];
    if ((t & 63) == 0) red[t >> 6] = ss;
    __syncthreads();
    float tot = red[0] + red[1] + red[2] + red[3];
    float inv = 16.0f / fmaxf(sqrtf(tot), 1e-12f);
    unsigned u = pk4(x[0]*inv, x[1]*inv, x[2]*inv, x[3]*inv);
    size_t addr = ((size_t)(row >> 5) * 16 + (t >> 4)) * 2048
                + (size_t)((t >> 3) & 1) * 1024
                + (size_t)(row & 31) * 32 + ((4 * t) & 31);
    *(unsigned int*)(out + addr) = u;
}

// ---------------------------------------------------------------------------
// offset [C=2048][D=1024] f32 -> offt FRAGMENT-LINEAR fp8 *64 (2^-6):
// rows = d (1024), K = c (2048), NT=32. Fused sum(offset^2) atomic. (r11-validated)
// ---------------------------------------------------------------------------
__global__ __launch_bounds__(256) void transpose_off(const float* __restrict__ off,
                                                     unsigned char* __restrict__ offt,
                                                     float* __restrict__ reg_out){
    __shared__ unsigned char t_lds[64][68];
    const int t  = threadIdx.x;
    const int c0 = blockIdx.x * 64;
    const int d0 = blockIdx.y * 64;
    float ss = 0.f;
    #pragma unroll
    for (int p = 0; p < 4; ++p){
        int c  = p * 16 + (t >> 4);
        int dq = t & 15;
        f32x4 v = *(const f32x4*)(off + (size_t)(c0 + c) * 1024 + d0 + dq * 4);
        ss += v[0]*v[0] + v[1]*v[1] + v[2]*v[2] + v[3]*v[3];
        unsigned u = pk4(v[0]*64.0f, v[1]*64.0f, v[2]*64.0f, v[3]*64.0f);
        #pragma unroll
        for (int j = 0; j < 4; ++j) t_lds[dq * 4 + j][c] = (unsigned char)(u >> (8*j));
    }
    __syncthreads();
    #pragma unroll
    for (int i = 0; i < 4; ++i){
        int byte_o = (t + 256 * i) * 4;
        int fs  = byte_o >> 11;
        int rem = byte_o & 2047;
        int dl  = fs * 32 + ((rem >> 5) & 31);
        int cl  = ((rem >> 10) & 1) * 32 + (rem & 31);
        unsigned int v = *(const unsigned int*)&t_lds[dl][cl];
        size_t f = (size_t)((d0 >> 5) + fs);
        *(unsigned int*)(offt + (f * 32 + (c0 >> 6)) * 2048 + rem) = v;
    }
    #pragma unroll
    for (int o = 32; o > 0; o >>= 1) ss += __shfl_xor(ss, o);
    __shared__ float red[4];
    if ((t & 63) == 0) red[t >> 6] = ss;
    __syncthreads();
    if (t == 0) atomicAdd(reg_out, red[0] + red[1] + red[2] + red[3]);
}

// ---------------------------------------------------------------------------
// GEMM1 (r13-validated hybrid): A row-major via LDS, B frag-linear global.
// 256x256 tile, 512 thr (8 waves 2Mx4N, wave 128x64). A tri-buffer 48KB.
// EPI==1: Wout = e4m3(exp(10*acc-10)*1024) row-major (ldw bytes)
// ---------------------------------------------------------------------------
template<int EPI, int SA, int SB>
__global__ __launch_bounds__(512, 2)
void gemm_hyb(const unsigned char* __restrict__ A, int lda,
              const unsigned char* __restrict__ B,
              int K,
              unsigned char* __restrict__ Wout, int ldw,
              const float* __restrict__ Cadd, float* __restrict__ Fout, int ldo)
{
    extern __shared__ char smem[];
    const int tid = threadIdx.x;
    int bx = blockIdx.x, by = blockIdx.y;
    {
        const int gx = gridDim.x, gy = gridDim.y;
        const int nwg = gx * gy;
        if ((nwg & 7) == 0){
            const int lid = bx + gx * by;
            const int q   = nwg >> 3;
            const int n   = (lid & 7) * q + (lid >> 3);
            const int sh  = 31 - __clz(gy);
            bx = n >> sh;
            by = n & (gy - 1);
        }
    }
    const int m0  = bx * 256;
    const int n0  = by * 256;
    const int wid = tid >> 6, lane = tid & 63;
    const int wr  = wid >> 2, wc = wid & 3;
    const int l31 = lane & 31, hg = lane >> 5;
    const int NT  = K >> 6;

    const int srow = tid >> 2;
    const int sg   = (tid & 3) ^ ((tid >> 3) & 3);
    const unsigned char* sA = A + (size_t)(m0 + srow) * lda + sg * 16;
    const int lp = tid * 16;
    auto stgA = [&](int buf, int ke){
        char* wb = smem + buf * 16384;
        gload16(sA + ke, wb + lp);
        gload16(sA + (size_t)128 * lda + ke, wb + 8192 + lp);
    };

    int aoff[4][2];
    #pragma unroll
    for (int m = 0; m < 4; ++m){
        int row = wr * 128 + m * 32 + l31;
        int sw  = (row >> 1) & 3;
        aoff[m][0] = row * 64 + (((hg << 1) | 0) ^ sw) * 16;
        aoff[m][1] = row * 64 + (((hg << 1) | 1) ^ sw) * 16;
    }
    const char* pB[2];
    #pragma unroll
    for (int n = 0; n < 2; ++n)
        pB[n] = (const char*)B
              + (size_t)(((n0 + wc * 64 + n * 32) >> 5) * NT) * 2048 + lane * 32;

    f32x16 acc[4][2] = {};
    i32x8 fa[4], bcur[2], bnxt[2];

#define MFMA8(bv) { __builtin_amdgcn_s_setprio(1); \
    _Pragma("unroll") for (int mi = 0; mi < 4; ++mi) \
    _Pragma("unroll") for (int ni = 0; ni < 2; ++ni) \
        acc[mi][ni] = __builtin_amdgcn_mfma_scale_f32_32x32x64_f8f6f4( \
            fa[mi], bv[ni], acc[mi][ni], 0, 0, 0, SA, 0, SB); \
    __builtin_amdgcn_s_setprio(0); }

    stgA(0, 0);
    stgA(1, 64);
    #pragma unroll
    for (int n = 0; n < 2; ++n) bcur[n] = ld_frag(pB[n], pB[n] + 16);
    VMW(6);
    GBAR();

    int bufc = 0;
    #pragma unroll 1
    for (int t = 0; t < NT - 1; ++t){
        const char* rb = smem + bufc * 16384;
        #pragma unroll
        for (int m = 0; m < 4; ++m)
            fa[m] = ld_frag(rb + aoff[m][0], rb + aoff[m][1]);
        {
            const size_t o = (size_t)(t + 1) * 2048;
            #pragma unroll
            for (int n = 0; n < 2; ++n) bnxt[n] = ld_frag(pB[n] + o, pB[n] + o + 16);
        }
        MFMA8(bcur);
        VMW(4);
        GBAR();
        if (t + 2 < NT){
            int bs = bufc + 2; if (bs >= 3) bs -= 3;
            stgA(bs, (t + 2) * 64);
        }
        bcur[0] = bnxt[0]; bcur[1] = bnxt[1];
        ++bufc; if (bufc == 3) bufc = 0;
    }
    {
        const char* rb = smem + bufc * 16384;
        #pragma unroll
        for (int m = 0; m < 4; ++m)
            fa[m] = ld_frag(rb + aoff[m][0], rb + aoff[m][1]);
        MFMA8(bcur);
    }
#undef MFMA8

    asm volatile("s_nop 7\n\ts_nop 7");

    #pragma unroll
    for (int m = 0; m < 4; ++m){
        #pragma unroll
        for (int n = 0; n < 2; ++n){
            const int grb = m0 + wr * 128 + m * 32;
            const int gc  = n0 + wc * 64  + n * 32 + l31;
            if (EPI == 1){
                #pragma unroll
                for (int q = 0; q < 4; ++q){
                    const int row0 = grb + 8 * q + 4 * hg;
                    float w0 = exp2f(fmaf(14.4269504f, acc[m][n][4*q+0], -4.4269504f));
                    float w1 = exp2f(fmaf(14.4269504f, acc[m][n][4*q+1], -4.4269504f));
                    float w2 = exp2f(fmaf(14.4269504f, acc[m][n][4*q+2], -4.4269504f));
                    float w3 = exp2f(fmaf(14.4269504f, acc[m][n][4*q+3], -4.4269504f));
                    unsigned u = pk4(w0, w1, w2, w3);
                    unsigned char* p = Wout + (size_t)row0 * ldw + gc;
                    p[0]                = (unsigned char)u;
                    p[(size_t)ldw]      = (unsigned char)(u >> 8);
                    p[(size_t)ldw * 2]  = (unsigned char)(u >> 16);
                    p[(size_t)ldw * 3]  = (unsigned char)(u >> 24);
                }
            } else {
                #pragma unroll
                for (int r = 0; r < 16; ++r){
                    const int row = (r & 3) + 8 * (r >> 2) + 4 * hg;
                    Fout[(size_t)(grb + row) * ldo + gc] =
                        Cadd[(size_t)(grb + row) * ldo + gc] + acc[m][n][r];
                }
            }
        }
    }
}

// ---------------------------------------------------------------------------
// GEMM2 + FUSED ROW-NORM (register-diet rev of r14):
// out[64 rows][1024] = l2norm(inp + W.offt^T) per row.
// 512 thr = 8 waves 2Mx4N; wave 32 rows x 256 cols; acc[8] x f32x16 (AGPR).
// A = W row-major fp8: DOUBLE-buffered 2x16KB LDS units of 64 rows x 256B
//   (4 k-tiles), slot swizzle p ^= row&15 via pre-swizzled source (rows+32
//   have identical swizzle since 32 % 16 == 0). Stage(u+1) at kk==1; 32 B
//   loads issue after it -> VMW(32) at unit end retires the 2 DMAs only.
// B = offt frag-linear, SINGLE base pointer + compile-time n*65536 offsets;
//   rotating bb[8]: each frag reloaded for kt t+1 right after its MFMA
//   (issue-to-use ~8 MFMA slots ~550cyc > L2 latency).
// Register budget: acc 128 (AGPR) + bb 64 + fa 8 + aoff 8 + ~20 misc ~ 230.
// Epilogue: v = inp + acc; row-ss via 5-step shfl_xor + LDS cross-wc reduce;
// write normalized out. Eliminates the separate 268MB norm pass.
// ---------------------------------------------------------------------------
template<int SA, int SB>
__global__ __launch_bounds__(512, 2)
void gemm_norm(const unsigned char* __restrict__ W,      // [rows][2048] fp8
               const unsigned char* __restrict__ Boff,   // frag-linear NT=32
               const float* __restrict__ inp,
               float* __restrict__ out)
{
    extern __shared__ char smem[];             // 2 x 16 KiB
    const int tid = threadIdx.x;
    int b = blockIdx.x;
    {   // 1D bijective XCD swizzle (grid % 8 == 0)
        const int nwg = gridDim.x;
        if ((nwg & 7) == 0){ const int q = nwg >> 3; b = (b & 7) * q + (b >> 3); }
    }
    const int r0  = b * 64;
    const int wid = tid >> 6, lane = tid & 63;
    const int wr  = wid >> 2, wc = wid & 3;    // 2M x 4N; wave 32 x 256
    const int l31 = lane & 31, hg = lane >> 5;
    const int NT  = 32;                        // k-tiles (2048 B / 64 B)
    const int NU  = 8;                         // units of 4 k-tiles

    // ---- A staging: unit = 64 rows x 16 slots(16B). thread -> rows
    // (tid>>4) and (tid>>4)+32, phys slot tid&15 holds logical slot
    // (tid&15)^(row&15); rows r and r+32 share the swizzle (32%16==0).
    const int s_row = tid >> 4;                // 0..31
    const int s_col = ((tid & 15) ^ (s_row & 15)) * 16;
    auto stgA = [&](int buf, int u){
        char* wb = smem + buf * 16384;
        const unsigned char* base = W + (size_t)u * 256 + s_col;
        gload16(base + (size_t)(r0 + s_row)      * 2048, wb + tid * 16);
        gload16(base + (size_t)(r0 + 32 + s_row) * 2048, wb + 8192 + tid * 16);
    };

    // ---- A frag ds offsets per kk (unit-relative, swizzled) ----
    int aoff[4][2];
    {
        const int row = wr * 32 + l31;
        const int sw  = row & 15;
        #pragma unroll
        for (int kk = 0; kk < 4; ++kk){
            aoff[kk][0] = row * 256 + ((kk * 4 + hg * 2 + 0) ^ sw) * 16;
            aoff[kk][1] = row * 256 + ((kk * 4 + hg * 2 + 1) ^ sw) * 16;
        }
    }

    // ---- B: single base; col-block n at compile-time offset n*NT*2048 ----
    const char* pBb = (const char*)Boff + (size_t)(wc * 8) * NT * 2048 + lane * 32;

    f32x16 acc[8] = {};
    i32x8 fa, bb[8];

    // ---- prologue: stage unit 0 (2 DMAs); load B(kt 0) (16 loads) ----
    stgA(0, 0);
    #pragma unroll
    for (int n = 0; n < 8; ++n)
        bb[n] = ld_frag(pBb + (size_t)n * (NT * 2048),
                        pBb + (size_t)n * (NT * 2048) + 16);
    VMW(16);                                   // retire the 2 A DMAs
    GBAR();

    #pragma unroll 1
    for (int u = 0; u < NU; ++u){
        const char* rb = smem + (u & 1) * 16384;
        #pragma unroll
        for (int kk = 0; kk < 4; ++kk){
            const int t = u * 4 + kk;
            fa = ld_frag(rb + aoff[kk][0], rb + aoff[kk][1]);
            const size_t on = (size_t)(t + 1 < NT ? t + 1 : NT - 1) * 2048;
            #pragma unroll
            for (int n = 0; n < 8; ++n){
                __builtin_amdgcn_s_setprio(1);
                acc[n] = __builtin_amdgcn_mfma_scale_f32_32x32x64_f8f6f4(
                    fa, bb[n], acc[n], 0, 0, 0, SA, 0, SB);
                __builtin_amdgcn_s_setprio(0);
                bb[n] = ld_frag(pBb + (size_t)n * (NT * 2048) + on,
                                pBb + (size_t)n * (NT * 2048) + on + 16);
            }
            if (kk == 1 && u + 1 < NU) stgA((u + 1) & 1, u + 1);
        }
        // FIFO since stgA(u+1): 32 B loads (kk=2,3) -> VMW(32) retires DMAs.
        VMW(32);
        GBAR();
    }

    asm volatile("s_nop 7\n\ts_nop 7");

    // ---- fused epilogue: v = inp + acc; row l2-norm; write out ----
    // C/D: col = l31 (+n*32 +wc*256), row = (r&3) + 8*(r>>2) + 4*hg (in [0,32))
    float ss[16];
    #pragma unroll
    for (int r = 0; r < 16; ++r) ss[r] = 0.f;
    const int grow0 = r0 + wr * 32;
    #pragma unroll
    for (int n = 0; n < 8; ++n){
        const int col = wc * 256 + n * 32 + l31;
        #pragma unroll
        for (int r = 0; r < 16; ++r){
            const int row = (r & 3) + 8 * (r >> 2) + 4 * hg;
            float vv = inp[(size_t)(grow0 + row) * 1024 + col] + acc[n][r];
            acc[n][r] = vv;
            ss[r] += vv * vv;
        }
    }
    #pragma unroll
    for (int m = 1; m <= 16; m <<= 1)
        #pragma unroll
        for (int r = 0; r < 16; ++r) ss[r] += __shfl_xor(ss[r], m);

    float* ssb = (float*)smem;                 // [64 rows][4 wc] = 1 KiB
    GBAR();                                    // k-loop LDS reads all retired
    if (l31 == 0){
        #pragma unroll
        for (int r = 0; r < 16; ++r){
            const int row = (r & 3) + 8 * (r >> 2) + 4 * hg;
            ssb[(wr * 32 + row) * 4 + wc] = ss[r];
        }
    }
    GBAR();
    #pragma unroll
    for (int r = 0; r < 16; ++r){
        const int row = (r & 3) + 8 * (r >> 2) + 4 * hg;
        const float* q = &ssb[(wr * 32 + row) * 4];
        float tot = q[0] + q[1] + q[2] + q[3];
        float inv = 1.0f / fmaxf(sqrtf(tot), 1e-12f);
        const size_t rbase = (size_t)(grow0 + row) * 1024;
        #pragma unroll
        for (int n = 0; n < 8; ++n){
            const int col = wc * 256 + n * 32 + l31;
            out[rbase + col] = acc[n][r] * inv;
        }
    }
}

// ---------------------------------------------------------------------------
extern "C" void kernel_launch(void* const* d_in, const int* in_sizes, int n_in,
                              void* d_out, int out_size, void* d_ws, size_t ws_size,
                              hipStream_t stream)
{
    (void)n_in; (void)out_size;
    const float* inp = (const float*)d_in[0];
    const float* pos = (const float*)d_in[1];
    const float* off = (const float*)d_in[2];
    float* out = (float*)d_out;

    const int D = 1024, C = 2048;
    const int N = in_sizes[0] / D;            // 32768

    // workspace (bytes): b_fp8(frag-lin)[C*D] | offt(frag-lin)[D*C]
    //                  | a_fp8(row-major)[Mc*D] | w_buf(row-major)[Mc*C]
    unsigned char* b_fp8 = (unsigned char*)d_ws;
    unsigned char* offt  = b_fp8 + (size_t)C * D;
    unsigned char* a_fp8 = offt + (size_t)D * C;
    size_t fixed = (size_t)C * D * 2;
    size_t avail = ws_size > fixed ? ws_size - fixed : 0;
    int Mc = 256;
    for (int cand = N; cand >= 256; cand >>= 1){
        if ((size_t)cand * (size_t)(D + C) <= avail){ Mc = cand; break; }
    }
    if (Mc > N) Mc = N;
    unsigned char* w_buf = a_fp8 + (size_t)Mc * D;

    hipFuncSetAttribute(reinterpret_cast<const void*>(&gemm_hyb<1,123,123>),
                        hipFuncAttributeMaxDynamicSharedMemorySize, 49152);
    hipFuncSetAttribute(reinterpret_cast<const void*>(&gemm_norm<117,121>),
                        hipFuncAttributeMaxDynamicSharedMemorySize, 32768);

    float* reg_out = out + (size_t)N * D;
    hipMemsetAsync(reg_out, 0, sizeof(float), stream);

    transpose_off<<<dim3(C / 64, D / 64), 256, 0, stream>>>(off, offt, reg_out);
    norm_rows_fp8_fl<<<C, 256, 0, stream>>>(pos, b_fp8);

    // scales (e8m0, 2^(b-127)): GEMM1 a,pos *16 -> 123,123;
    // GEMM2 W *1024 -> 117, offt *64 -> 121.
    for (int r0 = 0; r0 < N; r0 += Mc){
        norm_rows_fp8_rm<<<Mc, 256, 0, stream>>>(inp + (size_t)r0 * D, (unsigned int*)a_fp8);
        // GEMM1: W[Mc][C] = e4m3(1024 * exp(10*(a.b^T) - 10)), row-major
        gemm_hyb<1,123,123><<<dim3(Mc / 256, C / 256), 512, 49152, stream>>>(
            a_fp8, D, b_fp8, D, w_buf, C, nullptr, nullptr, 0);
        // GEMM2 + fused row-norm: out[Mc][D] = l2norm(inp + W.offt^T)
        gemm_norm<117,121><<<Mc / 64, 512, 32768, stream>>>(
            w_buf, offt, inp + (size_t)r0 * D, out + (size_t)r0 * D);
    }
}

// Round 16
// 512.215 us; speedup vs baseline: 1.9651x; 1.2278x over previous
//
#include <hip/hip_runtime.h>

typedef float  f32x4  __attribute__((ext_vector_type(4)));
typedef float  f32x16 __attribute__((ext_vector_type(16)));
typedef int    i32x4  __attribute__((ext_vector_type(4)));
typedef int    i32x8  __attribute__((ext_vector_type(8)));

#define AS1 __attribute__((address_space(1)))
#define AS3 __attribute__((address_space(3)))

// ---- software float -> OCP e4m3fn (RNE), valid for |x| <= 448 ----
__device__ __forceinline__ unsigned int f2e4m3(float x){
    union{float f; unsigned u;} v; v.f = x;
    unsigned s = (v.u >> 24) & 0x80u;
    float ax = fabsf(x);
    if (ax > 448.0f) ax = 448.0f;
    if (ax < 0.015625f){
        int d = (int)__builtin_rintf(ax * 512.0f);
        return s | (unsigned)d;
    }
    v.f = ax;
    unsigned u = v.u + 0x7ffffu + ((v.u >> 20) & 1u);
    unsigned E = (u >> 23) - 120u;
    unsigned M = (u >> 20) & 7u;
    return s | (E << 3) | M;
}

// ---- 4 floats -> packed 4x e4m3 (HW cvt if available) ----
__device__ __forceinline__ unsigned int pk4(float x0, float x1, float x2, float x3){
#if __has_builtin(__builtin_amdgcn_cvt_pk_fp8_f32)
    int u = __builtin_amdgcn_cvt_pk_fp8_f32(x0, x1, 0, false);
    u     = __builtin_amdgcn_cvt_pk_fp8_f32(x2, x3, u, true);
    return (unsigned)u;
#else
    return f2e4m3(x0) | (f2e4m3(x1) << 8) | (f2e4m3(x2) << 16) | (f2e4m3(x3) << 24);
#endif
}

__device__ __forceinline__ void gload16(const unsigned char* g, const char* l){
    __builtin_amdgcn_global_load_lds((const AS1 void*)g, (AS3 void*)l, 16, 0, 0);
}

__device__ __forceinline__ i32x8 ld_frag(const char* p0, const char* p1){
    i32x4 lo = *(const i32x4*)p0;
    i32x4 hi = *(const i32x4*)p1;
    return __builtin_shufflevector(lo, hi, 0,1,2,3,4,5,6,7);
}

#define GBAR() do{ asm volatile("" ::: "memory"); __builtin_amdgcn_s_barrier(); \
                   asm volatile("" ::: "memory"); }while(0)
#define VMW(N)  asm volatile("s_waitcnt vmcnt(" #N ")" ::: "memory")

// ---------------------------------------------------------------------------
// Row l2-normalize [rows][1024] f32 -> fp8 e4m3 *16 (2^-4), ROW-MAJOR.
// ---------------------------------------------------------------------------
__global__ __launch_bounds__(256) void norm_rows_fp8_rm(const float* __restrict__ in,
                                                        unsigned int* __restrict__ out){
    const int row = blockIdx.x;
    const int t   = threadIdx.x;
    f32x4 x = ((const f32x4*)(in + (size_t)row * 1024))[t];
    float ss = x[0]*x[0] + x[1]*x[1] + x[2]*x[2] + x[3]*x[3];
    #pragma unroll
    for (int o = 32; o > 0; o >>= 1) ss += __shfl_xor(ss, o);
    __shared__ float red[4];
    if ((t & 63) == 0) red[t >> 6] = ss;
    __syncthreads();
    float tot = red[0] + red[1] + red[2] + red[3];
    float inv = 16.0f / fmaxf(sqrtf(tot), 1e-12f);
    out[(size_t)row * 256 + t] = pk4(x[0]*inv, x[1]*inv, x[2]*inv, x[3]*inv);
}

// ---------------------------------------------------------------------------
// Row l2-normalize [rows][1024] f32 -> fp8 e4m3 *16 (2^-4), FRAGMENT-LINEAR
// NT=16. chunk(f,t)=2048B at ((row>>5)*16+t)*2048; lane l: row l&31, k-half l>>5.
// ---------------------------------------------------------------------------
__global__ __launch_bounds__(256) void norm_rows_fp8_fl(const float* __restrict__ in,
                                                        unsigned char* __restrict__ out){
    const int row = blockIdx.x;
    const int t   = threadIdx.x;
    f32x4 x = ((const f32x4*)(in + (size_t)row * 1024))[t];
    float ss = x[0]*x[0] + x[1]*x[1] + x[2]*x[2] + x[3]*x[3];
    #pragma unroll
    for (int o = 32; o > 0; o >>= 1) ss += __shfl_xor(ss, o);
    __shared__ float red[4];
    if ((t & 63) == 0) red[t >> 6] = ss;
    __syncthreads();
    float tot = red[0] + red[1] + red[2] + red[3];
    float inv = 16.0f / fmaxf(sqrtf(tot), 1e-12f);
    unsigned u = pk4(x[0]*inv, x[1]*inv, x[2]*inv, x[3]*inv);
    size_t addr = ((size_t)(row >> 5) * 16 + (t >> 4)) * 2048
                + (size_t)((t >> 3) & 1) * 1024
                + (size_t)(row & 31) * 32 + ((4 * t) & 31);
    *(unsigned int*)(out + addr) = u;
}

// ---------------------------------------------------------------------------
// offset [C=2048][D=1024] f32 -> offt FRAGMENT-LINEAR fp8 *64 (2^-6):
// rows = d (1024), K = c (2048), NT=32. Fused sum(offset^2) atomic. (r11-validated)
// ---------------------------------------------------------------------------
__global__ __launch_bounds__(256) void transpose_off(const float* __restrict__ off,
                                                     unsigned char* __restrict__ offt,
                                                     float* __restrict__ reg_out){
    __shared__ unsigned char t_lds[64][68];
    const int t  = threadIdx.x;
    const int c0 = blockIdx.x * 64;
    const int d0 = blockIdx.y * 64;
    float ss = 0.f;
    #pragma unroll
    for (int p = 0; p < 4; ++p){
        int c  = p * 16 + (t >> 4);
        int dq = t & 15;
        f32x4 v = *(const f32x4*)(off + (size_t)(c0 + c) * 1024 + d0 + dq * 4);
        ss += v[0]*v[0] + v[1]*v[1] + v[2]*v[2] + v[3]*v[3];
        unsigned u = pk4(v[0]*64.0f, v[1]*64.0f, v[2]*64.0f, v[3]*64.0f);
        #pragma unroll
        for (int j = 0; j < 4; ++j) t_lds[dq * 4 + j][c] = (unsigned char)(u >> (8*j));
    }
    __syncthreads();
    #pragma unroll
    for (int i = 0; i < 4; ++i){
        int byte_o = (t + 256 * i) * 4;
        int fs  = byte_o >> 11;
        int rem = byte_o & 2047;
        int dl  = fs * 32 + ((rem >> 5) & 31);
        int cl  = ((rem >> 10) & 1) * 32 + (rem & 31);
        unsigned int v = *(const unsigned int*)&t_lds[dl][cl];
        size_t f = (size_t)((d0 >> 5) + fs);
        *(unsigned int*)(offt + (f * 32 + (c0 >> 6)) * 2048 + rem) = v;
    }
    #pragma unroll
    for (int o = 32; o > 0; o >>= 1) ss += __shfl_xor(ss, o);
    __shared__ float red[4];
    if ((t & 63) == 0) red[t >> 6] = ss;
    __syncthreads();
    if (t == 0) atomicAdd(reg_out, red[0] + red[1] + red[2] + red[3]);
}

// ---------------------------------------------------------------------------
// GEMM1 (r13-validated hybrid): A row-major via LDS, B frag-linear global.
// 256x256 tile, 512 thr (8 waves 2Mx4N, wave 128x64). A tri-buffer 48KB.
// EPI==1: Wout = e4m3(exp(10*acc-10)*1024) row-major (ldw bytes)
// ---------------------------------------------------------------------------
template<int EPI, int SA, int SB>
__global__ __launch_bounds__(512, 2)
void gemm_hyb(const unsigned char* __restrict__ A, int lda,
              const unsigned char* __restrict__ B,
              int K,
              unsigned char* __restrict__ Wout, int ldw,
              const float* __restrict__ Cadd, float* __restrict__ Fout, int ldo)
{
    extern __shared__ char smem[];
    const int tid = threadIdx.x;
    int bx = blockIdx.x, by = blockIdx.y;
    {
        const int gx = gridDim.x, gy = gridDim.y;
        const int nwg = gx * gy;
        if ((nwg & 7) == 0){
            const int lid = bx + gx * by;
            const int q   = nwg >> 3;
            const int n   = (lid & 7) * q + (lid >> 3);
            const int sh  = 31 - __clz(gy);
            bx = n >> sh;
            by = n & (gy - 1);
        }
    }
    const int m0  = bx * 256;
    const int n0  = by * 256;
    const int wid = tid >> 6, lane = tid & 63;
    const int wr  = wid >> 2, wc = wid & 3;
    const int l31 = lane & 31, hg = lane >> 5;
    const int NT  = K >> 6;

    const int srow = tid >> 2;
    const int sg   = (tid & 3) ^ ((tid >> 3) & 3);
    const unsigned char* sA = A + (size_t)(m0 + srow) * lda + sg * 16;
    const int lp = tid * 16;
    auto stgA = [&](int buf, int ke){
        char* wb = smem + buf * 16384;
        gload16(sA + ke, wb + lp);
        gload16(sA + (size_t)128 * lda + ke, wb + 8192 + lp);
    };

    int aoff[4][2];
    #pragma unroll
    for (int m = 0; m < 4; ++m){
        int row = wr * 128 + m * 32 + l31;
        int sw  = (row >> 1) & 3;
        aoff[m][0] = row * 64 + (((hg << 1) | 0) ^ sw) * 16;
        aoff[m][1] = row * 64 + (((hg << 1) | 1) ^ sw) * 16;
    }
    const char* pB[2];
    #pragma unroll
    for (int n = 0; n < 2; ++n)
        pB[n] = (const char*)B
              + (size_t)(((n0 + wc * 64 + n * 32) >> 5) * NT) * 2048 + lane * 32;

    f32x16 acc[4][2] = {};
    i32x8 fa[4], bcur[2], bnxt[2];

#define MFMA8(bv) { __builtin_amdgcn_s_setprio(1); \
    _Pragma("unroll") for (int mi = 0; mi < 4; ++mi) \
    _Pragma("unroll") for (int ni = 0; ni < 2; ++ni) \
        acc[mi][ni] = __builtin_amdgcn_mfma_scale_f32_32x32x64_f8f6f4( \
            fa[mi], bv[ni], acc[mi][ni], 0, 0, 0, SA, 0, SB); \
    __builtin_amdgcn_s_setprio(0); }

    stgA(0, 0);
    stgA(1, 64);
    #pragma unroll
    for (int n = 0; n < 2; ++n) bcur[n] = ld_frag(pB[n], pB[n] + 16);
    VMW(6);
    GBAR();

    int bufc = 0;
    #pragma unroll 1
    for (int t = 0; t < NT - 1; ++t){
        const char* rb = smem + bufc * 16384;
        #pragma unroll
        for (int m = 0; m < 4; ++m)
            fa[m] = ld_frag(rb + aoff[m][0], rb + aoff[m][1]);
        {
            const size_t o = (size_t)(t + 1) * 2048;
            #pragma unroll
            for (int n = 0; n < 2; ++n) bnxt[n] = ld_frag(pB[n] + o, pB[n] + o + 16);
        }
        MFMA8(bcur);
        VMW(4);
        GBAR();
        if (t + 2 < NT){
            int bs = bufc + 2; if (bs >= 3) bs -= 3;
            stgA(bs, (t + 2) * 64);
        }
        bcur[0] = bnxt[0]; bcur[1] = bnxt[1];
        ++bufc; if (bufc == 3) bufc = 0;
    }
    {
        const char* rb = smem + bufc * 16384;
        #pragma unroll
        for (int m = 0; m < 4; ++m)
            fa[m] = ld_frag(rb + aoff[m][0], rb + aoff[m][1]);
        MFMA8(bcur);
    }
#undef MFMA8

    asm volatile("s_nop 7\n\ts_nop 7");

    #pragma unroll
    for (int m = 0; m < 4; ++m){
        #pragma unroll
        for (int n = 0; n < 2; ++n){
            const int grb = m0 + wr * 128 + m * 32;
            const int gc  = n0 + wc * 64  + n * 32 + l31;
            if (EPI == 1){
                #pragma unroll
                for (int q = 0; q < 4; ++q){
                    const int row0 = grb + 8 * q + 4 * hg;
                    float w0 = exp2f(fmaf(14.4269504f, acc[m][n][4*q+0], -4.4269504f));
                    float w1 = exp2f(fmaf(14.4269504f, acc[m][n][4*q+1], -4.4269504f));
                    float w2 = exp2f(fmaf(14.4269504f, acc[m][n][4*q+2], -4.4269504f));
                    float w3 = exp2f(fmaf(14.4269504f, acc[m][n][4*q+3], -4.4269504f));
                    unsigned u = pk4(w0, w1, w2, w3);
                    unsigned char* p = Wout + (size_t)row0 * ldw + gc;
                    p[0]                = (unsigned char)u;
                    p[(size_t)ldw]      = (unsigned char)(u >> 8);
                    p[(size_t)ldw * 2]  = (unsigned char)(u >> 16);
                    p[(size_t)ldw * 3]  = (unsigned char)(u >> 24);
                }
            } else {
                #pragma unroll
                for (int r = 0; r < 16; ++r){
                    const int row = (r & 3) + 8 * (r >> 2) + 4 * hg;
                    Fout[(size_t)(grb + row) * ldo + gc] =
                        Cadd[(size_t)(grb + row) * ldo + gc] + acc[m][n][r];
                }
            }
        }
    }
}

// ---------------------------------------------------------------------------
// GEMM2 + FUSED ROW-NORM, register-diet v2 (bb[4] rotation):
// out[64 rows][1024] = l2norm(inp + W.offt^T) per row.
// 512 thr = 8 waves 2Mx4N; wave 32 rows x 256 cols; acc[8] x f32x16 = 128
// (AGPR side of the 256-reg unified budget at (512,2)); arch-VGPR live set
// kept ~90 <= 128: bb[4]=32 + fa 8 + aoff 8 + ptrs/loop ~25 + ss 16 (epi).
// Per k-tile t: batch1 MFMA acc[0..3] with bb[j]=frag(n=j,t), refill slot j
// with frag(n=j+4,t); batch2 MFMA acc[4..7], refill with frag(n=j,t+1).
// Issue-to-use = 4 MFMAs (~276 cyc) > L2 latency. A = W row-major via
// double-buffered 2x16KB LDS units (4 k-tiles, slot swizzle p^=row&15 via
// pre-swizzled source); stage(u+1) at kk==1; 32 B-loads follow -> VMW(32)
// at unit end retires exactly the 2 DMAs. Epilogue as r15.
// ---------------------------------------------------------------------------
template<int SA, int SB>
__global__ __launch_bounds__(512, 2)
void gemm_norm(const unsigned char* __restrict__ W,      // [rows][2048] fp8
               const unsigned char* __restrict__ Boff,   // frag-linear NT=32
               const float* __restrict__ inp,
               float* __restrict__ out)
{
    extern __shared__ char smem[];             // 2 x 16 KiB
    const int tid = threadIdx.x;
    int b = blockIdx.x;
    {   // 1D bijective XCD swizzle (grid % 8 == 0)
        const int nwg = gridDim.x;
        if ((nwg & 7) == 0){ const int q = nwg >> 3; b = (b & 7) * q + (b >> 3); }
    }
    const int r0  = b * 64;
    const int wid = tid >> 6, lane = tid & 63;
    const int wr  = wid >> 2, wc = wid & 3;    // 2M x 4N; wave 32 x 256
    const int l31 = lane & 31, hg = lane >> 5;
    const int NT  = 32;                        // k-tiles (2048 B / 64 B)
    const int NU  = 8;                         // units of 4 k-tiles

    // ---- A staging: unit = 64 rows x 16 slots(16B); phys slot tid&15 of a
    // row holds logical (tid&15)^(row&15); rows r, r+32 share swizzle.
    const int s_row = tid >> 4;                // 0..31
    const int s_col = ((tid & 15) ^ (s_row & 15)) * 16;
    auto stgA = [&](int buf, int u){
        char* wb = smem + buf * 16384;
        const unsigned char* base = W + (size_t)u * 256 + s_col;
        gload16(base + (size_t)(r0 + s_row)      * 2048, wb + tid * 16);
        gload16(base + (size_t)(r0 + 32 + s_row) * 2048, wb + 8192 + tid * 16);
    };

    // ---- A frag ds offsets per kk (unit-relative, swizzled) ----
    int aoff[4][2];
    {
        const int row = wr * 32 + l31;
        const int sw  = row & 15;
        #pragma unroll
        for (int kk = 0; kk < 4; ++kk){
            aoff[kk][0] = row * 256 + ((kk * 4 + hg * 2 + 0) ^ sw) * 16;
            aoff[kk][1] = row * 256 + ((kk * 4 + hg * 2 + 1) ^ sw) * 16;
        }
    }

    // ---- B: single base; col-block n at compile-time offset n*NT*2048 ----
    const char* pBb = (const char*)Boff + (size_t)(wc * 8) * (NT * 2048) + lane * 32;

    f32x16 acc[8] = {};
    i32x8 fa, bb[4];

    // ---- prologue: stage unit 0 (2 DMAs); load slots n=0..3 of k-tile 0 ----
    stgA(0, 0);
    #pragma unroll
    for (int j = 0; j < 4; ++j)
        bb[j] = ld_frag(pBb + (size_t)j * (NT * 2048),
                        pBb + (size_t)j * (NT * 2048) + 16);
    VMW(8);                                    // retire the 2 A DMAs
    GBAR();

    #pragma unroll 1
    for (int u = 0; u < NU; ++u){
        const char* rb = smem + (u & 1) * 16384;
        #pragma unroll
        for (int kk = 0; kk < 4; ++kk){
            const int t = u * 4 + kk;
            fa = ld_frag(rb + aoff[kk][0], rb + aoff[kk][1]);
            const size_t cur = (size_t)t * 2048;
            const size_t nxt = (size_t)(t + 1 < NT ? t + 1 : NT - 1) * 2048;
            // batch 1: consume frags n=0..3 (tile t); refill with n=j+4 (tile t)
            #pragma unroll
            for (int j = 0; j < 4; ++j){
                __builtin_amdgcn_s_setprio(1);
                acc[j] = __builtin_amdgcn_mfma_scale_f32_32x32x64_f8f6f4(
                    fa, bb[j], acc[j], 0, 0, 0, SA, 0, SB);
                __builtin_amdgcn_s_setprio(0);
                bb[j] = ld_frag(pBb + (size_t)(j + 4) * (NT * 2048) + cur,
                                pBb + (size_t)(j + 4) * (NT * 2048) + cur + 16);
            }
            // batch 2: consume frags n=4..7 (tile t); refill with n=j (tile t+1)
            #pragma unroll
            for (int j = 0; j < 4; ++j){
                __builtin_amdgcn_s_setprio(1);
                acc[j + 4] = __builtin_amdgcn_mfma_scale_f32_32x32x64_f8f6f4(
                    fa, bb[j], acc[j + 4], 0, 0, 0, SA, 0, SB);
                __builtin_amdgcn_s_setprio(0);
                bb[j] = ld_frag(pBb + (size_t)j * (NT * 2048) + nxt,
                                pBb + (size_t)j * (NT * 2048) + nxt + 16);
            }
            if (kk == 1 && u + 1 < NU) stgA((u + 1) & 1, u + 1);
        }
        // FIFO since stgA(u+1): kk=2,3 issue 32 B loads -> VMW(32) retires DMAs.
        VMW(32);
        GBAR();
    }

    asm volatile("s_nop 7\n\ts_nop 7");

    // ---- fused epilogue: v = inp + acc; row l2-norm; write out ----
    // C/D: col = l31 (+n*32 +wc*256), row = (r&3) + 8*(r>>2) + 4*hg (in [0,32))
    float ss[16];
    #pragma unroll
    for (int r = 0; r < 16; ++r) ss[r] = 0.f;
    const int grow0 = r0 + wr * 32;
    #pragma unroll
    for (int n = 0; n < 8; ++n){
        const int col = wc * 256 + n * 32 + l31;
        #pragma unroll
        for (int r = 0; r < 16; ++r){
            const int row = (r & 3) + 8 * (r >> 2) + 4 * hg;
            float vv = inp[(size_t)(grow0 + row) * 1024 + col] + acc[n][r];
            acc[n][r] = vv;
            ss[r] += vv * vv;
        }
    }
    #pragma unroll
    for (int m = 1; m <= 16; m <<= 1)
        #pragma unroll
        for (int r = 0; r < 16; ++r) ss[r] += __shfl_xor(ss[r], m);

    float* ssb = (float*)smem;                 // [64 rows][4 wc] = 1 KiB
    GBAR();                                    // k-loop LDS reads all retired
    if (l31 == 0){
        #pragma unroll
        for (int r = 0; r < 16; ++r){
            const int row = (r & 3) + 8 * (r >> 2) + 4 * hg;
            ssb[(wr * 32 + row) * 4 + wc] = ss[r];
        }
    }
    GBAR();
    #pragma unroll
    for (int r = 0; r < 16; ++r){
        const int row = (r & 3) + 8 * (r >> 2) + 4 * hg;
        const float* q = &ssb[(wr * 32 + row) * 4];
        float tot = q[0] + q[1] + q[2] + q[3];
        float inv = 1.0f / fmaxf(sqrtf(tot), 1e-12f);
        const size_t rbase = (size_t)(grow0 + row) * 1024;
        #pragma unroll
        for (int n = 0; n < 8; ++n){
            const int col = wc * 256 + n * 32 + l31;
            out[rbase + col] = acc[n][r] * inv;
        }
    }
}

// ---------------------------------------------------------------------------
extern "C" void kernel_launch(void* const* d_in, const int* in_sizes, int n_in,
                              void* d_out, int out_size, void* d_ws, size_t ws_size,
                              hipStream_t stream)
{
    (void)n_in; (void)out_size;
    const float* inp = (const float*)d_in[0];
    const float* pos = (const float*)d_in[1];
    const float* off = (const float*)d_in[2];
    float* out = (float*)d_out;

    const int D = 1024, C = 2048;
    const int N = in_sizes[0] / D;            // 32768

    // workspace (bytes): b_fp8(frag-lin)[C*D] | offt(frag-lin)[D*C]
    //                  | a_fp8(row-major)[Mc*D] | w_buf(row-major)[Mc*C]
    unsigned char* b_fp8 = (unsigned char*)d_ws;
    unsigned char* offt  = b_fp8 + (size_t)C * D;
    unsigned char* a_fp8 = offt + (size_t)D * C;
    size_t fixed = (size_t)C * D * 2;
    size_t avail = ws_size > fixed ? ws_size - fixed : 0;
    int Mc = 256;
    for (int cand = N; cand >= 256; cand >>= 1){
        if ((size_t)cand * (size_t)(D + C) <= avail){ Mc = cand; break; }
    }
    if (Mc > N) Mc = N;
    unsigned char* w_buf = a_fp8 + (size_t)Mc * D;

    hipFuncSetAttribute(reinterpret_cast<const void*>(&gemm_hyb<1,123,123>),
                        hipFuncAttributeMaxDynamicSharedMemorySize, 49152);
    hipFuncSetAttribute(reinterpret_cast<const void*>(&gemm_norm<117,121>),
                        hipFuncAttributeMaxDynamicSharedMemorySize, 32768);

    float* reg_out = out + (size_t)N * D;
    hipMemsetAsync(reg_out, 0, sizeof(float), stream);

    transpose_off<<<dim3(C / 64, D / 64), 256, 0, stream>>>(off, offt, reg_out);
    norm_rows_fp8_fl<<<C, 256, 0, stream>>>(pos, b_fp8);

    // scales (e8m0, 2^(b-127)): GEMM1 a,pos *16 -> 123,123;
    // GEMM2 W *1024 -> 117, offt *64 -> 121.
    for (int r0 = 0; r0 < N; r0 += Mc){
        norm_rows_fp8_rm<<<Mc, 256, 0, stream>>>(inp + (size_t)r0 * D, (unsigned int*)a_fp8);
        // GEMM1: W[Mc][C] = e4m3(1024 * exp(10*(a.b^T) - 10)), row-major
        gemm_hyb<1,123,123><<<dim3(Mc / 256, C / 256), 512, 49152, stream>>>(
            a_fp8, D, b_fp8, D, w_buf, C, nullptr, nullptr, 0);
        // GEMM2 + fused row-norm: out[Mc][D] = l2norm(inp + W.offt^T)
        gemm_norm<117,121><<<Mc / 64, 512, 32768, stream>>>(
            w_buf, offt, inp + (size_t)r0 * D, out + (size_t)r0 * D);
    }
}

// Round 17
// 279.061 us; speedup vs baseline: 3.6070x; 1.8355x over previous
//
#include <hip/hip_runtime.h>

typedef float  f32x4  __attribute__((ext_vector_type(4)));
typedef float  f32x16 __attribute__((ext_vector_type(16)));
typedef int    i32x4  __attribute__((ext_vector_type(4)));
typedef int    i32x8  __attribute__((ext_vector_type(8)));

#define AS1 __attribute__((address_space(1)))
#define AS3 __attribute__((address_space(3)))

// ---- software float -> OCP e4m3fn (RNE), valid for |x| <= 448 ----
__device__ __forceinline__ unsigned int f2e4m3(float x){
    union{float f; unsigned u;} v; v.f = x;
    unsigned s = (v.u >> 24) & 0x80u;
    float ax = fabsf(x);
    if (ax > 448.0f) ax = 448.0f;
    if (ax < 0.015625f){
        int d = (int)__builtin_rintf(ax * 512.0f);
        return s | (unsigned)d;
    }
    v.f = ax;
    unsigned u = v.u + 0x7ffffu + ((v.u >> 20) & 1u);
    unsigned E = (u >> 23) - 120u;
    unsigned M = (u >> 20) & 7u;
    return s | (E << 3) | M;
}

// ---- 4 floats -> packed 4x e4m3 (HW cvt if available) ----
__device__ __forceinline__ unsigned int pk4(float x0, float x1, float x2, float x3){
#if __has_builtin(__builtin_amdgcn_cvt_pk_fp8_f32)
    int u = __builtin_amdgcn_cvt_pk_fp8_f32(x0, x1, 0, false);
    u     = __builtin_amdgcn_cvt_pk_fp8_f32(x2, x3, u, true);
    return (unsigned)u;
#else
    return f2e4m3(x0) | (f2e4m3(x1) << 8) | (f2e4m3(x2) << 16) | (f2e4m3(x3) << 24);
#endif
}

__device__ __forceinline__ void gload16(const unsigned char* g, const char* l){
    __builtin_amdgcn_global_load_lds((const AS1 void*)g, (AS3 void*)l, 16, 0, 0);
}

__device__ __forceinline__ i32x8 ld_frag(const char* p0, const char* p1){
    i32x4 lo = *(const i32x4*)p0;
    i32x4 hi = *(const i32x4*)p1;
    return __builtin_shufflevector(lo, hi, 0,1,2,3,4,5,6,7);
}

#define GBAR() do{ asm volatile("" ::: "memory"); __builtin_amdgcn_s_barrier(); \
                   asm volatile("" ::: "memory"); }while(0)
#define VMW(N)  asm volatile("s_waitcnt vmcnt(" #N ")" ::: "memory")

// ---------------------------------------------------------------------------
// Row l2-normalize [rows][1024] f32 -> fp8 e4m3 scaled by 16 (MX scale 2^-4).
// ---------------------------------------------------------------------------
__global__ __launch_bounds__(256) void norm_rows_fp8(const float* __restrict__ in,
                                                     unsigned int* __restrict__ out){
    const int row = blockIdx.x;
    const int t   = threadIdx.x;
    f32x4 x = ((const f32x4*)(in + (size_t)row * 1024))[t];
    float ss = x[0]*x[0] + x[1]*x[1] + x[2]*x[2] + x[3]*x[3];
    #pragma unroll
    for (int o = 32; o > 0; o >>= 1) ss += __shfl_xor(ss, o);
    __shared__ float red[4];
    if ((t & 63) == 0) red[t >> 6] = ss;
    __syncthreads();
    float tot = red[0] + red[1] + red[2] + red[3];
    float inv = 16.0f / fmaxf(sqrtf(tot), 1e-12f);
    out[(size_t)row * 256 + t] = pk4(x[0]*inv, x[1]*inv, x[2]*inv, x[3]*inv);
}

// ---------------------------------------------------------------------------
// Final in-place row l2-normalize of d_out [N][1024] f32.
// ---------------------------------------------------------------------------
__global__ __launch_bounds__(256) void norm_rows_f32(float* __restrict__ buf){
    const int row = blockIdx.x;
    const int t   = threadIdx.x;
    f32x4* p = (f32x4*)(buf + (size_t)row * 1024);
    f32x4 x = p[t];
    float ss = x[0]*x[0] + x[1]*x[1] + x[2]*x[2] + x[3]*x[3];
    #pragma unroll
    for (int o = 32; o > 0; o >>= 1) ss += __shfl_xor(ss, o);
    __shared__ float red[4];
    if ((t & 63) == 0) red[t >> 6] = ss;
    __syncthreads();
    float tot = red[0] + red[1] + red[2] + red[3];
    float inv = 1.0f / fmaxf(sqrtf(tot), 1e-12f);
    p[t] = x * inv;
}

// ---------------------------------------------------------------------------
// offset [C=2048][D=1024] f32 -> offt [D][C] fp8 e4m3 scaled by 64 (2^-6),
// fused sum(offset^2) -> atomicAdd(reg_out). Tile: 64(c) x 64(d).
// ---------------------------------------------------------------------------
__global__ __launch_bounds__(256) void transpose_off(const float* __restrict__ off,
                                                     unsigned char* __restrict__ offt,
                                                     float* __restrict__ reg_out){
    __shared__ unsigned char t_lds[64][68];
    const int t  = threadIdx.x;
    const int c0 = blockIdx.x * 64;
    const int d0 = blockIdx.y * 64;
    float ss = 0.f;
    #pragma unroll
    for (int p = 0; p < 4; ++p){
        int c  = p * 16 + (t >> 4);
        int dq = t & 15;
        f32x4 v = *(const f32x4*)(off + (size_t)(c0 + c) * 1024 + d0 + dq * 4);
        ss += v[0]*v[0] + v[1]*v[1] + v[2]*v[2] + v[3]*v[3];
        unsigned u = pk4(v[0]*64.0f, v[1]*64.0f, v[2]*64.0f, v[3]*64.0f);
        #pragma unroll
        for (int j = 0; j < 4; ++j) t_lds[dq * 4 + j][c] = (unsigned char)(u >> (8*j));
    }
    __syncthreads();
    #pragma unroll
    for (int p = 0; p < 4; ++p){
        int d  = p * 16 + (t >> 4);
        int cq = t & 15;
        unsigned int o = *(const unsigned int*)&t_lds[d][cq * 4];
        *(unsigned int*)(offt + (size_t)(d0 + d) * 2048 + c0 + cq * 4) = o;
    }
    #pragma unroll
    for (int o = 32; o > 0; o >>= 1) ss += __shfl_xor(ss, o);
    __shared__ float red[4];
    if ((t & 63) == 0) red[t >> 6] = ss;
    __syncthreads();
    if (t == 0) atomicAdd(reg_out, red[0] + red[1] + red[2] + red[3]);
}

// ---------------------------------------------------------------------------
// FP8 GEMM: acc[m][n] = 2^(SA-127)*2^(SB-127) * sum_k A[m][k]*B[n][k]
// (A,B fp8 e4m3, K-contiguous rows; lda/ldb in BYTES.)
// 256x128 tile, BK=64, 256 threads (4 waves 2Mx2N; wave tile 128x64) ->
// 72 KiB LDS (best-measured r9 config). mfma_scale_f32_32x32x64_f8f6f4,
// uniform scales. Tri-buffered LDS (3 x [A 16KB | B 8KB]); stage->consume
// distance = 2 K-tiles (> HBM lat). One barrier + one counted VMW(6) per
// K-tile; no lgkmcnt drains (builtin MFMA => compiler-counted lgkm).
// Granule swizzle g ^= (row>>1)&3 via pre-swizzled global source.
// Safety: stage(t+2) overwrites buf read at t-1; every wave's t-1 reads
// completed before its t-1 MFMAs, which precede GBAR(t-1) -> safe.
// EPI==1: Wout = e4m3(exp(10*acc-10)*1024) via exp2+cvt_pk  (ldw bytes)
// EPI==2: Fout = Cadd + acc                                  (ldo floats)
// ---------------------------------------------------------------------------
template<int EPI, int SA, int SB>
__global__ __launch_bounds__(256, 2)
void gemm256(const unsigned char* __restrict__ A, int lda,
             const unsigned char* __restrict__ B, int ldb,
             int K,
             unsigned char* __restrict__ Wout, int ldw,
             const float* __restrict__ Cadd, float* __restrict__ Fout, int ldo)
{
    extern __shared__ char smem[];             // 3 x 24 KiB
    const int tid  = threadIdx.x;

    // ---- XCD-aware bijective remap ----
    int bx = blockIdx.x, by = blockIdx.y;
    {
        const int gx = gridDim.x, gy = gridDim.y;
        const int nwg = gx * gy;
        if ((nwg & 7) == 0){
            const int lid = bx + gx * by;
            const int q   = nwg >> 3;
            const int n   = (lid & 7) * q + (lid >> 3);
            const int sh  = 31 - __clz(gy);    // gy is a power of two
            bx = n >> sh;
            by = n & (gy - 1);
        }
    }
    const int m0   = bx * 256;
    const int n0   = by * 128;
    const int wid  = tid >> 6, lane = tid & 63;
    const int wr   = wid >> 1, wc = wid & 1;   // 2x2 waves, wave tile 128x64
    const int l31  = lane & 31, hg = lane >> 5;

    // ---- staging: A 16KB (256 rows x 64B), B 8KB (128 rows x 64B) ----
    // thread t -> rows (t>>2)+64j, phys granule t&3 holds logical
    // (t&3)^((row>>1)&3); +64 rows preserves the XOR -> one sg for all j.
    const int srow = tid >> 2;
    const int sg   = (tid & 3) ^ ((tid >> 3) & 3);
    const unsigned char* sA = A + (size_t)(m0 + srow) * lda + sg * 16;
    const unsigned char* sB = B + (size_t)(n0 + srow) * ldb + sg * 16;
    const int lp = tid * 16;

    auto stgA = [&](char* wb, int ke){
        #pragma unroll
        for (int j = 0; j < 4; ++j)
            gload16(sA + (size_t)j * 64 * lda + ke, wb + j * 4096 + lp);
    };
    auto stgB = [&](char* wb, int ke){
        #pragma unroll
        for (int j = 0; j < 2; ++j)
            gload16(sB + (size_t)j * 64 * ldb + ke, wb + 16384 + j * 4096 + lp);
    };

    // ---- frag read offsets (swizzled): lane row = base + l31, 32 k-bytes
    // = 2 b128 at granules (2hg+j) ^ ((row>>1)&3) ----
    int aoff[4][2], boff[2][2];
    #pragma unroll
    for (int m = 0; m < 4; ++m){
        int row = wr * 128 + m * 32 + l31;
        int sw  = (row >> 1) & 3;
        aoff[m][0] = row * 64 + (((hg << 1) | 0) ^ sw) * 16;
        aoff[m][1] = row * 64 + (((hg << 1) | 1) ^ sw) * 16;
    }
    #pragma unroll
    for (int n = 0; n < 2; ++n){
        int row = wc * 64 + n * 32 + l31;
        int sw  = (row >> 1) & 3;
        boff[n][0] = 16384 + row * 64 + (((hg << 1) | 0) ^ sw) * 16;
        boff[n][1] = 16384 + row * 64 + (((hg << 1) | 1) ^ sw) * 16;
    }

    f32x16 acc[4][2] = {};
    const int nsteps = K >> 6;                 // BK = 64

#define RD_A(mb) { \
    fa[0] = ld_frag(b0 + aoff[(mb)][0],   b0 + aoff[(mb)][1]); \
    fa[1] = ld_frag(b0 + aoff[(mb)+1][0], b0 + aoff[(mb)+1][1]); }
#define RD_B()   { \
    fb[0] = ld_frag(b0 + boff[0][0], b0 + boff[0][1]); \
    fb[1] = ld_frag(b0 + boff[1][0], b0 + boff[1][1]); }
#define MFMA4(mb) { __builtin_amdgcn_s_setprio(1); \
    _Pragma("unroll") for (int mi = 0; mi < 2; ++mi) \
    _Pragma("unroll") for (int ni = 0; ni < 2; ++ni) \
        acc[(mb)+mi][ni] = __builtin_amdgcn_mfma_scale_f32_32x32x64_f8f6f4( \
            fa[mi], fb[ni], acc[(mb)+mi][ni], 0, 0, 0, SA, 0, SB); \
    __builtin_amdgcn_s_setprio(0); }

    i32x8 fa[2], fb[2];
    char* b0 = smem;
    char* b1 = smem + 24576;
    char* b2 = smem + 49152;

    // ---- prologue: stage tiles 0,1 (12 loads); wait tile 0 (6) ----
    stgA(b0, 0);  stgB(b0, 0);
    stgA(b1, 64); stgB(b1, 64);
    VMW(6);
    GBAR();

    int ke = 128;                              // k-byte offset of tile t+2
    #pragma unroll 1
    for (int t = 0; t < nsteps - 2; ++t){
        RD_A(0); RD_B();
        stgA(b2, ke);
        MFMA4(0);
        RD_A(2);
        stgB(b2, ke);
        MFMA4(2);
        VMW(6);                                // drain tile t+1; keep t+2 in flight
        GBAR();
        char* tmp = b0; b0 = b1; b1 = b2; b2 = tmp;
        ke += 64;
    }
    // t = nsteps-2 (no staging; drain last tile's loads at end)
    RD_A(0); RD_B();
    MFMA4(0);
    RD_A(2);
    MFMA4(2);
    VMW(0);
    GBAR();
    // t = nsteps-1
    { char* tmp = b0; b0 = b1; b1 = tmp; }
    RD_A(0); RD_B();
    MFMA4(0);
    RD_A(2);
    MFMA4(2);

#undef RD_A
#undef RD_B
#undef MFMA4

    asm volatile("s_nop 7\n\ts_nop 7");

    // C/D layout (32x32): col = lane&31, row = (r&3) + 8*(r>>2) + 4*(lane>>5)
    #pragma unroll
    for (int m = 0; m < 4; ++m){
        #pragma unroll
        for (int n = 0; n < 2; ++n){
            const int grb = m0 + wr * 128 + m * 32;
            const int gc  = n0 + wc * 64  + n * 32 + l31;
            if (EPI == 1){
                #pragma unroll
                for (int q = 0; q < 4; ++q){
                    const int row0 = grb + 8 * q + 4 * hg;   // rows row0..row0+3
                    float w0 = exp2f(fmaf(14.4269504f, acc[m][n][4*q+0], -4.4269504f));
                    float w1 = exp2f(fmaf(14.4269504f, acc[m][n][4*q+1], -4.4269504f));
                    float w2 = exp2f(fmaf(14.4269504f, acc[m][n][4*q+2], -4.4269504f));
                    float w3 = exp2f(fmaf(14.4269504f, acc[m][n][4*q+3], -4.4269504f));
                    unsigned u = pk4(w0, w1, w2, w3);
                    unsigned char* p = Wout + (size_t)row0 * ldw + gc;
                    p[0]                = (unsigned char)u;
                    p[(size_t)ldw]      = (unsigned char)(u >> 8);
                    p[(size_t)ldw * 2]  = (unsigned char)(u >> 16);
                    p[(size_t)ldw * 3]  = (unsigned char)(u >> 24);
                }
            } else {
                #pragma unroll
                for (int r = 0; r < 16; ++r){
                    const int row = (r & 3) + 8 * (r >> 2) + 4 * hg;
                    Fout[(size_t)(grb + row) * ldo + gc] =
                        Cadd[(size_t)(grb + row) * ldo + gc] + acc[m][n][r];
                }
            }
        }
    }
}

// ---------------------------------------------------------------------------
extern "C" void kernel_launch(void* const* d_in, const int* in_sizes, int n_in,
                              void* d_out, int out_size, void* d_ws, size_t ws_size,
                              hipStream_t stream)
{
    (void)n_in; (void)out_size;
    const float* inp = (const float*)d_in[0];
    const float* pos = (const float*)d_in[1];
    const float* off = (const float*)d_in[2];
    float* out = (float*)d_out;

    const int D = 1024, C = 2048;
    const int N = in_sizes[0] / D;            // 32768

    // workspace (bytes): b_fp8[C*D] | offt[D*C] | a_fp8[Mc*D] | w_buf[Mc*C]
    unsigned char* b_fp8 = (unsigned char*)d_ws;
    unsigned char* offt  = b_fp8 + (size_t)C * D;
    unsigned char* a_fp8 = offt + (size_t)D * C;
    size_t fixed = (size_t)C * D * 2;
    size_t avail = ws_size > fixed ? ws_size - fixed : 0;
    int Mc = 256;
    for (int cand = N; cand >= 256; cand >>= 1){
        if ((size_t)cand * (size_t)(D + C) <= avail){ Mc = cand; break; }
    }
    if (Mc > N) Mc = N;
    unsigned char* w_buf = a_fp8 + (size_t)Mc * D;

    // scales (e8m0, 2^(b-127)): GEMM1 a,pos *16 -> 123,123;
    // GEMM2 W *1024 -> 117, offt *64 -> 121.
    hipFuncSetAttribute(reinterpret_cast<const void*>(&gemm256<1,123,123>),
                        hipFuncAttributeMaxDynamicSharedMemorySize, 73728);
    hipFuncSetAttribute(reinterpret_cast<const void*>(&gemm256<2,117,121>),
                        hipFuncAttributeMaxDynamicSharedMemorySize, 73728);

    float* reg_out = out + (size_t)N * D;
    hipMemsetAsync(reg_out, 0, sizeof(float), stream);

    transpose_off<<<dim3(C / 64, D / 64), 256, 0, stream>>>(off, offt, reg_out);
    norm_rows_fp8<<<C, 256, 0, stream>>>(pos, (unsigned int*)b_fp8);

    for (int r0 = 0; r0 < N; r0 += Mc){
        norm_rows_fp8<<<Mc, 256, 0, stream>>>(inp + (size_t)r0 * D, (unsigned int*)a_fp8);
        // GEMM1: W[Mc][C] = e4m3(1024 * exp(10*(a.b^T) - 10))
        gemm256<1,123,123><<<dim3(Mc / 256, C / 128), 256, 73728, stream>>>(
            a_fp8, D, b_fp8, D, D, w_buf, C, nullptr, nullptr, 0);
        // GEMM2: out[Mc][D] = inp + (2^-16 scaled) W . offt^T
        gemm256<2,117,121><<<dim3(Mc / 256, D / 128), 256, 73728, stream>>>(
            w_buf, C, offt, C, C, nullptr, 0, inp + (size_t)r0 * D, out + (size_t)r0 * D, D);
    }
    norm_rows_f32<<<N, 256, 0, stream>>>(out);
}